// Round 2
// baseline (542.068 us; speedup 1.0000x reference)
//
#include <hip/hip_runtime.h>
#include <hip/hip_bf16.h>
#include <type_traits>

typedef __hip_bfloat16 bf16;
typedef __hip_bfloat162 bf162;
typedef short v8s __attribute__((ext_vector_type(8)));
typedef float v4f __attribute__((ext_vector_type(4)));

__device__ __forceinline__ float lrelu(float x) { return x > 0.f ? x : 0.2f * x; }
__device__ __forceinline__ float b2f(bf16 v) { return __bfloat162float(v); }

// ---------------- CSR build ----------------
__global__ void k_count(const int* __restrict__ ei, int* __restrict__ cnt, int E) {
    int i = blockIdx.x * 256 + threadIdx.x;
    if (i < E) atomicAdd(&cnt[ei[E + i]], 1);
}

__global__ void k_scan1(const int* __restrict__ cnt, int* __restrict__ ofs,
                        int* __restrict__ bsum, int n) {
    __shared__ int sh[256];
    int t = threadIdx.x;
    int base = blockIdx.x * 1024 + t * 4;
    int v[4]; int s = 0;
#pragma unroll
    for (int i = 0; i < 4; ++i) { v[i] = (base + i < n) ? cnt[base + i] : 0; s += v[i]; }
    sh[t] = s; __syncthreads();
    for (int o = 1; o < 256; o <<= 1) {
        int x = 0; if (t >= o) x = sh[t - o];
        __syncthreads();
        sh[t] += x;
        __syncthreads();
    }
    int excl = sh[t] - s;
#pragma unroll
    for (int i = 0; i < 4; ++i) { if (base + i < n) ofs[base + i] = excl; excl += v[i]; }
    if (t == 255) bsum[blockIdx.x] = sh[255];
}

__global__ void k_scan2(const int* __restrict__ bsum, int* __restrict__ bpre, int nb) {
    int l = threadIdx.x;                       // 64 threads, nb <= 64
    int v = (l < nb) ? bsum[l] : 0;
    int orig = v;
    for (int o = 1; o < 64; o <<= 1) {
        int x = __shfl_up(v, o);
        if (l >= o) v += x;
    }
    if (l < nb) bpre[l] = v - orig;
}

__global__ void k_scan3(int* __restrict__ ofs, int* __restrict__ cur,
                        const int* __restrict__ bpre, int n) {
    int i = blockIdx.x * 256 + threadIdx.x;
    if (i < n) { int v = ofs[i] + bpre[i >> 10]; ofs[i] = v; cur[i] = v; }
}

__global__ void k_fill(const int* __restrict__ ei, int* __restrict__ cur,
                       int* __restrict__ csr, int E) {
    int i = blockIdx.x * 256 + threadIdx.x;
    if (i < E) {
        int d = ei[E + i];
        int pos = atomicAdd(&cur[d], 1);
        csr[pos] = ei[i];
    }
}

// ---------------- weight transpose (f32 -> bf16) ----------------
__global__ void k_transpose(const float* __restrict__ s0, const float* __restrict__ s1,
                            const float* __restrict__ s2, const float* __restrict__ s3,
                            const float* __restrict__ s4, const float* __restrict__ s5,
                            bf16* __restrict__ wt) {
    const float* src;
    switch (blockIdx.x) {
        case 0: src = s0; break; case 1: src = s1; break; case 2: src = s2; break;
        case 3: src = s3; break; case 4: src = s4; break; default: src = s5; break;
    }
    bf16* dst = wt + blockIdx.x * 16384;
    for (int i = threadIdx.x; i < 16384; i += 256) {
        int k = i >> 7, n = i & 127;
        dst[n * 128 + k] = __float2bfloat16(src[i]);   // WT[n][k] = W[k][n]
    }
}

__global__ void k_params(const float* b1, const float* R1b, const float* g1, const float* be1,
                         const float* rm1, const float* rv1,
                         const float* b2, const float* R2b, const float* g2, const float* be2,
                         const float* rm2, const float* rv2,
                         const float* b3, const float* R3b, float* __restrict__ prm) {
    int c = threadIdx.x;
    if (c < 128) {
        float s1 = g1[c] * rsqrtf(rv1[c] + 1e-5f);
        prm[c]       = b1[c] + R1b[c];
        prm[128 + c] = s1;
        prm[256 + c] = be1[c] - rm1[c] * s1;
        float s2 = g2[c] * rsqrtf(rv2[c] + 1e-5f);
        prm[384 + c] = b2[c] + R2b[c];
        prm[512 + c] = s2;
        prm[640 + c] = be2[c] - rm2[c] * s2;
        prm[768 + c] = b3[c] + R3b[c];
    }
}

// ---------------- dual GEMM: O0 = A@W, O1 = A@R (both [n,128]@[128,128]) ----------------
// A is f32 (layer 1) or bf16 (layers 2/3); converted to bf16 in LDS. BT* pre-transposed bf16.
template <typename T>
__global__ void gemm_dual(const T* __restrict__ A,
                          const bf16* __restrict__ BT0, const bf16* __restrict__ BT1,
                          bf16* __restrict__ O0, bf16* __restrict__ O1, int nrows) {
    __shared__ bf16 Ash[128 * 128];   // 32 KB, XOR-swizzled 16B chunks
    __shared__ bf16 Bsh[128 * 128];   // 32 KB
    const bf16* BT = (blockIdx.y == 0) ? BT0 : BT1;
    bf16* O = (blockIdx.y == 0) ? O0 : O1;
    const int t = threadIdx.x;
    const int rowbase = blockIdx.x * 128;
    {
        const int r = t >> 1, hf = t & 1;
        int gr = rowbase + r; if (gr >= nrows) gr = nrows - 1;
        const float4* bsrc = (const float4*)(BT + r * 128 + hf * 64);
        if constexpr (std::is_same<T, float>::value) {
            const float4* asrc = (const float4*)(A + (size_t)gr * 128 + hf * 64);
#pragma unroll
            for (int j = 0; j < 8; ++j) {
                float4 u = asrc[2 * j], w = asrc[2 * j + 1];
                union { bf16 h[8]; float4 f; } tmp;
                tmp.h[0] = __float2bfloat16(u.x); tmp.h[1] = __float2bfloat16(u.y);
                tmp.h[2] = __float2bfloat16(u.z); tmp.h[3] = __float2bfloat16(u.w);
                tmp.h[4] = __float2bfloat16(w.x); tmp.h[5] = __float2bfloat16(w.y);
                tmp.h[6] = __float2bfloat16(w.z); tmp.h[7] = __float2bfloat16(w.w);
                int c = hf * 8 + j, cp = c ^ (r & 7);
                *(float4*)(&Ash[r * 128 + cp * 8]) = tmp.f;
                *(float4*)(&Bsh[r * 128 + cp * 8]) = bsrc[j];
            }
        } else {
            const float4* asrc = (const float4*)(A + (size_t)gr * 128 + hf * 64);
#pragma unroll
            for (int j = 0; j < 8; ++j) {
                int c = hf * 8 + j, cp = c ^ (r & 7);
                *(float4*)(&Ash[r * 128 + cp * 8]) = asrc[j];
                *(float4*)(&Bsh[r * 128 + cp * 8]) = bsrc[j];
            }
        }
    }
    __syncthreads();
    const int wave = t >> 6, lane = t & 63, quad = lane >> 4, l16 = lane & 15;
    v4f acc[2][8];
#pragma unroll
    for (int i = 0; i < 2; ++i)
#pragma unroll
        for (int j = 0; j < 8; ++j) acc[i][j] = (v4f){0.f, 0.f, 0.f, 0.f};
#pragma unroll
    for (int kit = 0; kit < 4; ++kit) {
        v8s afr[2], bfr[8];
#pragma unroll
        for (int rt = 0; rt < 2; ++rt) {
            int row = wave * 32 + rt * 16 + l16;
            int cp = (kit * 4 + quad) ^ (row & 7);
            afr[rt] = *(const v8s*)(&Ash[row * 128 + cp * 8]);
        }
#pragma unroll
        for (int ct = 0; ct < 8; ++ct) {
            int nn = ct * 16 + l16;
            int cp = (kit * 4 + quad) ^ (nn & 7);
            bfr[ct] = *(const v8s*)(&Bsh[nn * 128 + cp * 8]);
        }
#pragma unroll
        for (int rt = 0; rt < 2; ++rt)
#pragma unroll
            for (int ct = 0; ct < 8; ++ct)
                acc[rt][ct] = __builtin_amdgcn_mfma_f32_16x16x32_bf16(afr[rt], bfr[ct], acc[rt][ct], 0, 0, 0);
    }
#pragma unroll
    for (int rt = 0; rt < 2; ++rt)
#pragma unroll
        for (int ct = 0; ct < 8; ++ct)
#pragma unroll
            for (int r = 0; r < 4; ++r) {
                int gr = rowbase + wave * 32 + rt * 16 + quad * 4 + r;
                if (gr < nrows) O[(size_t)gr * 128 + ct * 16 + l16] = __float2bfloat16(acc[rt][ct][r]);
            }
}

// ---------------- attention-logit prep ----------------
__global__ void k_prep8(const bf16* __restrict__ xW, const float* __restrict__ asrc,
                        const float* __restrict__ adst,
                        float* __restrict__ es, float* __restrict__ ed, int n) {
    int wave = threadIdx.x >> 6, lane = threadIdx.x & 63;
    int node = blockIdx.x * 4 + wave;
    if (node >= n) return;
    bf162 xp = *(const bf162*)(xW + (size_t)node * 128 + 2 * lane);
    float2 sp = *(const float2*)(asrc + 2 * lane);
    float2 dp = *(const float2*)(adst + 2 * lane);
    float x0 = b2f(xp.x), x1 = b2f(xp.y);
    float ps = x0 * sp.x + x1 * sp.y;
    float pd = x0 * dp.x + x1 * dp.y;
    for (int o = 1; o < 8; o <<= 1) { ps += __shfl_xor(ps, o); pd += __shfl_xor(pd, o); }
    if ((lane & 7) == 0) {
        int h = lane >> 3;
        es[node * 8 + h] = ps;
        ed[node * 8 + h] = pd;
    }
}

__global__ void k_prep1(const bf16* __restrict__ xW, const float* __restrict__ asrc,
                        const float* __restrict__ adst,
                        float* __restrict__ es, float* __restrict__ ed, int n) {
    int wave = threadIdx.x >> 6, lane = threadIdx.x & 63;
    int node = blockIdx.x * 4 + wave;
    if (node >= n) return;
    bf162 xp = *(const bf162*)(xW + (size_t)node * 128 + 2 * lane);
    float2 sp = *(const float2*)(asrc + 2 * lane);
    float2 dp = *(const float2*)(adst + 2 * lane);
    float x0 = b2f(xp.x), x1 = b2f(xp.y);
    float ps = x0 * sp.x + x1 * sp.y;
    float pd = x0 * dp.x + x1 * dp.y;
    for (int o = 1; o < 64; o <<= 1) { ps += __shfl_xor(ps, o); pd += __shfl_xor(pd, o); }
    if (lane == 0) { es[node] = ps; ed[node] = pd; }
}

// ---------------- aggregation: 8 heads, fused bias+residual+BN+ReLU ----------------
__global__ void k_agg8(const bf16* __restrict__ xW, const float* __restrict__ es,
                       const float* __restrict__ ed,
                       const int* __restrict__ ofs, const int* __restrict__ cur,
                       const int* __restrict__ csr,
                       const bf16* __restrict__ rres, const float* __restrict__ prm,
                       bf16* __restrict__ hout, int n) {
    int wave = threadIdx.x >> 6, lane = threadIdx.x & 63;
    int node = blockIdx.x * 4 + wave;
    if (node >= n) return;
    int h = lane >> 3;
    float edv = ed[node * 8 + h];
    float eself = lrelu(es[node * 8 + h] + edv);
    float m = eself, den = 1.f;
    int beg = ofs[node], end = cur[node];
    for (int j = beg; j < end; ++j) {
        int s = csr[j];
        float e = lrelu(es[s * 8 + h] + edv);
        if (e > m) { den = den * __expf(m - e) + 1.f; m = e; }
        else den += __expf(e - m);
    }
    bf162 xp = *(const bf162*)(xW + (size_t)node * 128 + 2 * lane);
    float w = __expf(eself - m);
    float a0 = w * b2f(xp.x), a1 = w * b2f(xp.y);
    for (int j = beg; j < end; ++j) {
        int s = csr[j];
        float e = lrelu(es[s * 8 + h] + edv);
        float wj = __expf(e - m);
        bf162 p = *(const bf162*)(xW + (size_t)s * 128 + 2 * lane);
        a0 += wj * b2f(p.x);
        a1 += wj * b2f(p.y);
    }
    float inv = 1.f / den;
    int c0 = 2 * lane;
    bf162 rp = *(const bf162*)(rres + (size_t)node * 128 + c0);
    float v0 = a0 * inv + prm[c0] + b2f(rp.x);
    float v1 = a1 * inv + prm[c0 + 1] + b2f(rp.y);
    v0 = fmaxf(v0 * prm[128 + c0] + prm[256 + c0], 0.f);
    v1 = fmaxf(v1 * prm[128 + c0 + 1] + prm[256 + c0 + 1], 0.f);
    bf162 o; o.x = __float2bfloat16(v0); o.y = __float2bfloat16(v1);
    *(bf162*)(hout + (size_t)node * 128 + c0) = o;
}

// ---------------- aggregation: 1 head, fused bias+residual, writes final out (f32) ----------------
__global__ void k_agg1(const bf16* __restrict__ xW, const float* __restrict__ es,
                       const float* __restrict__ ed,
                       const int* __restrict__ ofs, const int* __restrict__ cur,
                       const int* __restrict__ csr,
                       const bf16* __restrict__ rres, const float* __restrict__ bias,
                       float* __restrict__ out, int n) {
    int wave = threadIdx.x >> 6, lane = threadIdx.x & 63;
    int node = blockIdx.x * 4 + wave;
    if (node >= n) return;
    float edv = ed[node];
    float eself = lrelu(es[node] + edv);
    float m = eself, den = 1.f;
    int beg = ofs[node], end = cur[node];
    for (int j = beg; j < end; ++j) {
        int s = csr[j];
        float e = lrelu(es[s] + edv);
        if (e > m) { den = den * __expf(m - e) + 1.f; m = e; }
        else den += __expf(e - m);
    }
    bf162 xp = *(const bf162*)(xW + (size_t)node * 128 + 2 * lane);
    float w = __expf(eself - m);
    float a0 = w * b2f(xp.x), a1 = w * b2f(xp.y);
    for (int j = beg; j < end; ++j) {
        int s = csr[j];
        float e = lrelu(es[s] + edv);
        float wj = __expf(e - m);
        bf162 p = *(const bf162*)(xW + (size_t)s * 128 + 2 * lane);
        a0 += wj * b2f(p.x);
        a1 += wj * b2f(p.y);
    }
    float inv = 1.f / den;
    int c0 = 2 * lane;
    bf162 rp = *(const bf162*)(rres + (size_t)node * 128 + c0);
    float2 o;
    o.x = a0 * inv + bias[c0] + b2f(rp.x);
    o.y = a1 * inv + bias[c0 + 1] + b2f(rp.y);
    *(float2*)(out + (size_t)node * 128 + c0) = o;
}

extern "C" void kernel_launch(void* const* d_in, const int* in_sizes, int n_in,
                              void* d_out, int out_size, void* d_ws, size_t ws_size,
                              hipStream_t stream) {
    const float* x   = (const float*)d_in[0];
    const int*   ei  = (const int*)d_in[1];
    const float* W1  = (const float*)d_in[2];
    const float* as1 = (const float*)d_in[3];
    const float* ad1 = (const float*)d_in[4];
    const float* b1  = (const float*)d_in[5];
    const float* W2  = (const float*)d_in[6];
    const float* as2 = (const float*)d_in[7];
    const float* ad2 = (const float*)d_in[8];
    const float* b2  = (const float*)d_in[9];
    const float* W3  = (const float*)d_in[10];
    const float* as3 = (const float*)d_in[11];
    const float* ad3 = (const float*)d_in[12];
    const float* b3  = (const float*)d_in[13];
    const float* R1w = (const float*)d_in[14];
    const float* R1b = (const float*)d_in[15];
    const float* R2w = (const float*)d_in[16];
    const float* R2b = (const float*)d_in[17];
    const float* R3w = (const float*)d_in[18];
    const float* R3b = (const float*)d_in[19];
    const float* g1  = (const float*)d_in[20];
    const float* be1 = (const float*)d_in[21];
    const float* rm1 = (const float*)d_in[22];
    const float* rv1 = (const float*)d_in[23];
    const float* g2  = (const float*)d_in[24];
    const float* be2 = (const float*)d_in[25];
    const float* rm2 = (const float*)d_in[26];
    const float* rv2 = (const float*)d_in[27];

    const int N = in_sizes[0] / 128;
    const int E = in_sizes[1] / 2;

    char* p = (char*)d_ws;
    size_t off = 0;
    auto alloc = [&](size_t b) { void* r = p + off; off = (off + b + 255) & ~(size_t)255; return r; };
    int*   cnt  = (int*)alloc((size_t)N * 4);
    int*   ofs  = (int*)alloc((size_t)N * 4);
    int*   cur  = (int*)alloc((size_t)N * 4);
    int*   bsum = (int*)alloc(64 * 4);
    int*   bpre = (int*)alloc(64 * 4);
    int*   csr  = (int*)alloc((size_t)E * 4);
    bf16*  WT   = (bf16*)alloc((size_t)6 * 16384 * 2);
    float* prm  = (float*)alloc(896 * 4);
    float* es   = (float*)alloc((size_t)N * 8 * 4);
    float* ed   = (float*)alloc((size_t)N * 8 * 4);
    bf16*  xW   = (bf16*)alloc((size_t)N * 128 * 2);
    bf16*  rres = (bf16*)alloc((size_t)N * 128 * 2);
    bf16*  hA   = (bf16*)alloc((size_t)N * 128 * 2);
    bf16*  hB   = (bf16*)alloc((size_t)N * 128 * 2);
    (void)ws_size; (void)n_in; (void)out_size;

    hipMemsetAsync(cnt, 0, (size_t)N * 4, stream);
    const int eb = (E + 255) / 256;
    const int nb = (N + 1023) / 1024;    // 49 <= 64
    k_count<<<eb, 256, 0, stream>>>(ei, cnt, E);
    k_scan1<<<nb, 256, 0, stream>>>(cnt, ofs, bsum, N);
    k_scan2<<<1, 64, 0, stream>>>(bsum, bpre, nb);
    k_scan3<<<(N + 255) / 256, 256, 0, stream>>>(ofs, cur, bpre, N);
    k_fill<<<eb, 256, 0, stream>>>(ei, cur, csr, E);
    k_transpose<<<6, 256, 0, stream>>>(W1, R1w, W2, R2w, W3, R3w, WT);
    k_params<<<1, 128, 0, stream>>>(b1, R1b, g1, be1, rm1, rv1,
                                    b2, R2b, g2, be2, rm2, rv2, b3, R3b, prm);

    const int gx = (N + 127) / 128;
    const int nw = (N + 3) / 4;
    // layer 1 (A = f32 x)
    gemm_dual<float><<<dim3(gx, 2), 256, 0, stream>>>(x, WT, WT + 16384, xW, rres, N);
    k_prep8<<<nw, 256, 0, stream>>>(xW, as1, ad1, es, ed, N);
    k_agg8<<<nw, 256, 0, stream>>>(xW, es, ed, ofs, cur, csr, rres, prm, hA, N);
    // layer 2
    gemm_dual<bf16><<<dim3(gx, 2), 256, 0, stream>>>(hA, WT + 2 * 16384, WT + 3 * 16384, xW, rres, N);
    k_prep8<<<nw, 256, 0, stream>>>(xW, as2, ad2, es, ed, N);
    k_agg8<<<nw, 256, 0, stream>>>(xW, es, ed, ofs, cur, csr, rres, prm + 384, hB, N);
    // layer 3
    gemm_dual<bf16><<<dim3(gx, 2), 256, 0, stream>>>(hB, WT + 4 * 16384, WT + 5 * 16384, xW, rres, N);
    k_prep1<<<nw, 256, 0, stream>>>(xW, as3, ad3, es, ed, N);
    k_agg1<<<nw, 256, 0, stream>>>(xW, es, ed, ofs, cur, csr, rres, prm + 768, (float*)d_out, N);
}

// Round 3
// 370.926 us; speedup vs baseline: 1.4614x; 1.4614x over previous
//
#include <hip/hip_runtime.h>
#include <hip/hip_bf16.h>
#include <type_traits>

typedef __hip_bfloat16 bf16;
typedef __hip_bfloat162 bf162;
typedef short v8s __attribute__((ext_vector_type(8)));
typedef float v4f __attribute__((ext_vector_type(4)));

__device__ __forceinline__ float lrelu(float x) { return x > 0.f ? x : 0.2f * x; }
__device__ __forceinline__ float b2f(bf16 v) { return __bfloat162float(v); }

// ---------------- CSR build ----------------
__global__ void k_count(const int* __restrict__ ei, int* __restrict__ cnt, int E) {
    int i = blockIdx.x * 256 + threadIdx.x;
    if (i < E) atomicAdd(&cnt[ei[E + i]], 1);
}

__global__ void k_scan1(const int* __restrict__ cnt, int* __restrict__ ofs,
                        int* __restrict__ bsum, int n) {
    __shared__ int sh[256];
    int t = threadIdx.x;
    int base = blockIdx.x * 1024 + t * 4;
    int v[4]; int s = 0;
#pragma unroll
    for (int i = 0; i < 4; ++i) { v[i] = (base + i < n) ? cnt[base + i] : 0; s += v[i]; }
    sh[t] = s; __syncthreads();
    for (int o = 1; o < 256; o <<= 1) {
        int x = 0; if (t >= o) x = sh[t - o];
        __syncthreads();
        sh[t] += x;
        __syncthreads();
    }
    int excl = sh[t] - s;
#pragma unroll
    for (int i = 0; i < 4; ++i) { if (base + i < n) ofs[base + i] = excl; excl += v[i]; }
    if (t == 255) bsum[blockIdx.x] = sh[255];
}

__global__ void k_scan2(const int* __restrict__ bsum, int* __restrict__ bpre, int nb) {
    int l = threadIdx.x;                       // 64 threads, nb <= 64
    int v = (l < nb) ? bsum[l] : 0;
    int orig = v;
    for (int o = 1; o < 64; o <<= 1) {
        int x = __shfl_up(v, o);
        if (l >= o) v += x;
    }
    if (l < nb) bpre[l] = v - orig;
}

__global__ void k_scan3(int* __restrict__ ofs, int* __restrict__ cur,
                        const int* __restrict__ bpre, int n) {
    int i = blockIdx.x * 256 + threadIdx.x;
    if (i < n) { int v = ofs[i] + bpre[i >> 10]; ofs[i] = v; cur[i] = v; }
}

__global__ void k_fill(const int* __restrict__ ei, int* __restrict__ cur,
                       int* __restrict__ csr, int E) {
    int i = blockIdx.x * 256 + threadIdx.x;
    if (i < E) {
        int d = ei[E + i];
        int pos = atomicAdd(&cur[d], 1);
        csr[pos] = ei[i];
    }
}

// ---------------- weight transpose (f32 -> bf16) ----------------
__global__ void k_transpose(const float* __restrict__ s0, const float* __restrict__ s1,
                            const float* __restrict__ s2, const float* __restrict__ s3,
                            const float* __restrict__ s4, const float* __restrict__ s5,
                            bf16* __restrict__ wt) {
    const float* src;
    switch (blockIdx.x) {
        case 0: src = s0; break; case 1: src = s1; break; case 2: src = s2; break;
        case 3: src = s3; break; case 4: src = s4; break; default: src = s5; break;
    }
    bf16* dst = wt + blockIdx.x * 16384;
    for (int i = threadIdx.x; i < 16384; i += 256) {
        int k = i >> 7, n = i & 127;
        dst[n * 128 + k] = __float2bfloat16(src[i]);   // WT[n][k] = W[k][n]
    }
}

__global__ void k_params(const float* b1, const float* R1b, const float* g1, const float* be1,
                         const float* rm1, const float* rv1,
                         const float* b2, const float* R2b, const float* g2, const float* be2,
                         const float* rm2, const float* rv2,
                         const float* b3, const float* R3b, float* __restrict__ prm) {
    int c = threadIdx.x;
    if (c < 128) {
        float s1 = g1[c] * rsqrtf(rv1[c] + 1e-5f);
        prm[c]       = b1[c] + R1b[c];
        prm[128 + c] = s1;
        prm[256 + c] = be1[c] - rm1[c] * s1;
        float s2 = g2[c] * rsqrtf(rv2[c] + 1e-5f);
        prm[384 + c] = b2[c] + R2b[c];
        prm[512 + c] = s2;
        prm[640 + c] = be2[c] - rm2[c] * s2;
        prm[768 + c] = b3[c] + R3b[c];
    }
}

// ---------------- dual GEMM: O0 = A@W, O1 = A@R (both [n,128]@[128,128]) ----------------
template <typename T>
__global__ void gemm_dual(const T* __restrict__ A,
                          const bf16* __restrict__ BT0, const bf16* __restrict__ BT1,
                          bf16* __restrict__ O0, bf16* __restrict__ O1, int nrows) {
    __shared__ bf16 Ash[128 * 128];   // 32 KB, XOR-swizzled 16B chunks
    __shared__ bf16 Bsh[128 * 128];   // 32 KB
    const bf16* BT = (blockIdx.y == 0) ? BT0 : BT1;
    bf16* O = (blockIdx.y == 0) ? O0 : O1;
    const int t = threadIdx.x;
    const int rowbase = blockIdx.x * 128;
    {
        const int r = t >> 1, hf = t & 1;
        int gr = rowbase + r; if (gr >= nrows) gr = nrows - 1;
        const float4* bsrc = (const float4*)(BT + r * 128 + hf * 64);
        if constexpr (std::is_same<T, float>::value) {
            const float4* asrc = (const float4*)(A + (size_t)gr * 128 + hf * 64);
#pragma unroll
            for (int j = 0; j < 8; ++j) {
                float4 u = asrc[2 * j], w = asrc[2 * j + 1];
                union { bf16 h[8]; float4 f; } tmp;
                tmp.h[0] = __float2bfloat16(u.x); tmp.h[1] = __float2bfloat16(u.y);
                tmp.h[2] = __float2bfloat16(u.z); tmp.h[3] = __float2bfloat16(u.w);
                tmp.h[4] = __float2bfloat16(w.x); tmp.h[5] = __float2bfloat16(w.y);
                tmp.h[6] = __float2bfloat16(w.z); tmp.h[7] = __float2bfloat16(w.w);
                int c = hf * 8 + j, cp = c ^ (r & 7);
                *(float4*)(&Ash[r * 128 + cp * 8]) = tmp.f;
                *(float4*)(&Bsh[r * 128 + cp * 8]) = bsrc[j];
            }
        } else {
            const float4* asrc = (const float4*)(A + (size_t)gr * 128 + hf * 64);
#pragma unroll
            for (int j = 0; j < 8; ++j) {
                int c = hf * 8 + j, cp = c ^ (r & 7);
                *(float4*)(&Ash[r * 128 + cp * 8]) = asrc[j];
                *(float4*)(&Bsh[r * 128 + cp * 8]) = bsrc[j];
            }
        }
    }
    __syncthreads();
    const int wave = t >> 6, lane = t & 63, quad = lane >> 4, l16 = lane & 15;
    v4f acc[2][8];
#pragma unroll
    for (int i = 0; i < 2; ++i)
#pragma unroll
        for (int j = 0; j < 8; ++j) acc[i][j] = (v4f){0.f, 0.f, 0.f, 0.f};
#pragma unroll
    for (int kit = 0; kit < 4; ++kit) {
        v8s afr[2], bfr[8];
#pragma unroll
        for (int rt = 0; rt < 2; ++rt) {
            int row = wave * 32 + rt * 16 + l16;
            int cp = (kit * 4 + quad) ^ (row & 7);
            afr[rt] = *(const v8s*)(&Ash[row * 128 + cp * 8]);
        }
#pragma unroll
        for (int ct = 0; ct < 8; ++ct) {
            int nn = ct * 16 + l16;
            int cp = (kit * 4 + quad) ^ (nn & 7);
            bfr[ct] = *(const v8s*)(&Bsh[nn * 128 + cp * 8]);
        }
#pragma unroll
        for (int rt = 0; rt < 2; ++rt)
#pragma unroll
            for (int ct = 0; ct < 8; ++ct)
                acc[rt][ct] = __builtin_amdgcn_mfma_f32_16x16x32_bf16(afr[rt], bfr[ct], acc[rt][ct], 0, 0, 0);
    }
#pragma unroll
    for (int rt = 0; rt < 2; ++rt)
#pragma unroll
        for (int ct = 0; ct < 8; ++ct)
#pragma unroll
            for (int r = 0; r < 4; ++r) {
                int gr = rowbase + wave * 32 + rt * 16 + quad * 4 + r;
                if (gr < nrows) O[(size_t)gr * 128 + ct * 16 + l16] = __float2bfloat16(acc[rt][ct][r]);
            }
}

// ---------------- attention-logit prep ----------------
__global__ void k_prep8(const bf16* __restrict__ xW, const float* __restrict__ asrc,
                        const float* __restrict__ adst,
                        float* __restrict__ es, float* __restrict__ ed, int n) {
    int wave = threadIdx.x >> 6, lane = threadIdx.x & 63;
    int node = blockIdx.x * 4 + wave;
    if (node >= n) return;
    bf162 xp = *(const bf162*)(xW + (size_t)node * 128 + 2 * lane);
    float2 sp = *(const float2*)(asrc + 2 * lane);
    float2 dp = *(const float2*)(adst + 2 * lane);
    float x0 = b2f(xp.x), x1 = b2f(xp.y);
    float ps = x0 * sp.x + x1 * sp.y;
    float pd = x0 * dp.x + x1 * dp.y;
    for (int o = 1; o < 8; o <<= 1) { ps += __shfl_xor(ps, o); pd += __shfl_xor(pd, o); }
    if ((lane & 7) == 0) {
        int h = lane >> 3;
        es[node * 8 + h] = ps;
        ed[node * 8 + h] = pd;
    }
}

__global__ void k_prep1(const bf16* __restrict__ xW, const float* __restrict__ asrc,
                        const float* __restrict__ adst,
                        float* __restrict__ es, float* __restrict__ ed, int n) {
    int wave = threadIdx.x >> 6, lane = threadIdx.x & 63;
    int node = blockIdx.x * 4 + wave;
    if (node >= n) return;
    bf162 xp = *(const bf162*)(xW + (size_t)node * 128 + 2 * lane);
    float2 sp = *(const float2*)(asrc + 2 * lane);
    float2 dp = *(const float2*)(adst + 2 * lane);
    float x0 = b2f(xp.x), x1 = b2f(xp.y);
    float ps = x0 * sp.x + x1 * sp.y;
    float pd = x0 * dp.x + x1 * dp.y;
    for (int o = 1; o < 64; o <<= 1) { ps += __shfl_xor(ps, o); pd += __shfl_xor(pd, o); }
    if (lane == 0) { es[node] = ps; ed[node] = pd; }
}

// ---------------- aggregation: ONE PASS (no max-sub; logits are tiny), 8 heads ----------------
__global__ void k_agg8(const bf16* __restrict__ xW, const float* __restrict__ es,
                       const float* __restrict__ ed,
                       const int* __restrict__ ofs, const int* __restrict__ cur,
                       const int* __restrict__ csr,
                       const bf16* __restrict__ rres, const float* __restrict__ prm,
                       bf16* __restrict__ hout, int n) {
    int wave = threadIdx.x >> 6, lane = threadIdx.x & 63;
    int node = blockIdx.x * 4 + wave;
    if (node >= n) return;
    int h = lane >> 3;
    float edv = ed[node * 8 + h];
    int beg = ofs[node], end = cur[node];
    bf162 xp = *(const bf162*)(xW + (size_t)node * 128 + 2 * lane);
    float wself = __expf(lrelu(es[node * 8 + h] + edv));
    float den = wself;
    float a0 = wself * b2f(xp.x), a1 = wself * b2f(xp.y);
    int j = beg;
    for (; j + 1 < end; j += 2) {
        int s0 = csr[j], s1 = csr[j + 1];
        float e0 = es[s0 * 8 + h], e1 = es[s1 * 8 + h];
        bf162 p0 = *(const bf162*)(xW + (size_t)s0 * 128 + 2 * lane);
        bf162 p1 = *(const bf162*)(xW + (size_t)s1 * 128 + 2 * lane);
        float w0 = __expf(lrelu(e0 + edv));
        float w1 = __expf(lrelu(e1 + edv));
        den += w0 + w1;
        a0 += w0 * b2f(p0.x) + w1 * b2f(p1.x);
        a1 += w0 * b2f(p0.y) + w1 * b2f(p1.y);
    }
    if (j < end) {
        int s = csr[j];
        float w = __expf(lrelu(es[s * 8 + h] + edv));
        bf162 p = *(const bf162*)(xW + (size_t)s * 128 + 2 * lane);
        den += w;
        a0 += w * b2f(p.x);
        a1 += w * b2f(p.y);
    }
    float inv = 1.f / den;
    int c0 = 2 * lane;
    bf162 rp = *(const bf162*)(rres + (size_t)node * 128 + c0);
    float v0 = a0 * inv + prm[c0] + b2f(rp.x);
    float v1 = a1 * inv + prm[c0 + 1] + b2f(rp.y);
    v0 = fmaxf(v0 * prm[128 + c0] + prm[256 + c0], 0.f);
    v1 = fmaxf(v1 * prm[128 + c0 + 1] + prm[256 + c0 + 1], 0.f);
    bf162 o; o.x = __float2bfloat16(v0); o.y = __float2bfloat16(v1);
    *(bf162*)(hout + (size_t)node * 128 + c0) = o;
}

// ---------------- aggregation: ONE PASS, 1 head, writes final out (f32) ----------------
__global__ void k_agg1(const bf16* __restrict__ xW, const float* __restrict__ es,
                       const float* __restrict__ ed,
                       const int* __restrict__ ofs, const int* __restrict__ cur,
                       const int* __restrict__ csr,
                       const bf16* __restrict__ rres, const float* __restrict__ bias,
                       float* __restrict__ out, int n) {
    int wave = threadIdx.x >> 6, lane = threadIdx.x & 63;
    int node = blockIdx.x * 4 + wave;
    if (node >= n) return;
    float edv = ed[node];
    int beg = ofs[node], end = cur[node];
    bf162 xp = *(const bf162*)(xW + (size_t)node * 128 + 2 * lane);
    float wself = __expf(lrelu(es[node] + edv));
    float den = wself;
    float a0 = wself * b2f(xp.x), a1 = wself * b2f(xp.y);
    int j = beg;
    for (; j + 1 < end; j += 2) {
        int s0 = csr[j], s1 = csr[j + 1];
        float e0 = es[s0], e1 = es[s1];
        bf162 p0 = *(const bf162*)(xW + (size_t)s0 * 128 + 2 * lane);
        bf162 p1 = *(const bf162*)(xW + (size_t)s1 * 128 + 2 * lane);
        float w0 = __expf(lrelu(e0 + edv));
        float w1 = __expf(lrelu(e1 + edv));
        den += w0 + w1;
        a0 += w0 * b2f(p0.x) + w1 * b2f(p1.x);
        a1 += w0 * b2f(p0.y) + w1 * b2f(p1.y);
    }
    if (j < end) {
        int s = csr[j];
        float w = __expf(lrelu(es[s] + edv));
        bf162 p = *(const bf162*)(xW + (size_t)s * 128 + 2 * lane);
        den += w;
        a0 += w * b2f(p.x);
        a1 += w * b2f(p.y);
    }
    float inv = 1.f / den;
    int c0 = 2 * lane;
    bf162 rp = *(const bf162*)(rres + (size_t)node * 128 + c0);
    float2 o;
    o.x = a0 * inv + bias[c0] + b2f(rp.x);
    o.y = a1 * inv + bias[c0 + 1] + b2f(rp.y);
    *(float2*)(out + (size_t)node * 128 + c0) = o;
}

extern "C" void kernel_launch(void* const* d_in, const int* in_sizes, int n_in,
                              void* d_out, int out_size, void* d_ws, size_t ws_size,
                              hipStream_t stream) {
    const float* x   = (const float*)d_in[0];
    const int*   ei  = (const int*)d_in[1];
    const float* W1  = (const float*)d_in[2];
    const float* as1 = (const float*)d_in[3];
    const float* ad1 = (const float*)d_in[4];
    const float* b1  = (const float*)d_in[5];
    const float* W2  = (const float*)d_in[6];
    const float* as2 = (const float*)d_in[7];
    const float* ad2 = (const float*)d_in[8];
    const float* b2  = (const float*)d_in[9];
    const float* W3  = (const float*)d_in[10];
    const float* as3 = (const float*)d_in[11];
    const float* ad3 = (const float*)d_in[12];
    const float* b3  = (const float*)d_in[13];
    const float* R1w = (const float*)d_in[14];
    const float* R1b = (const float*)d_in[15];
    const float* R2w = (const float*)d_in[16];
    const float* R2b = (const float*)d_in[17];
    const float* R3w = (const float*)d_in[18];
    const float* R3b = (const float*)d_in[19];
    const float* g1  = (const float*)d_in[20];
    const float* be1 = (const float*)d_in[21];
    const float* rm1 = (const float*)d_in[22];
    const float* rv1 = (const float*)d_in[23];
    const float* g2  = (const float*)d_in[24];
    const float* be2 = (const float*)d_in[25];
    const float* rm2 = (const float*)d_in[26];
    const float* rv2 = (const float*)d_in[27];

    const int N = in_sizes[0] / 128;
    const int E = in_sizes[1] / 2;

    char* p = (char*)d_ws;
    size_t off = 0;
    auto alloc = [&](size_t b) { void* r = p + off; off = (off + b + 255) & ~(size_t)255; return r; };
    int*   cnt  = (int*)alloc((size_t)N * 4);
    int*   ofs  = (int*)alloc((size_t)N * 4);
    int*   cur  = (int*)alloc((size_t)N * 4);
    int*   bsum = (int*)alloc(64 * 4);
    int*   bpre = (int*)alloc(64 * 4);
    int*   csr  = (int*)alloc((size_t)E * 4);
    bf16*  WT   = (bf16*)alloc((size_t)6 * 16384 * 2);
    float* prm  = (float*)alloc(896 * 4);
    float* es   = (float*)alloc((size_t)N * 8 * 4);
    float* ed   = (float*)alloc((size_t)N * 8 * 4);
    bf16*  xW   = (bf16*)alloc((size_t)N * 128 * 2);
    bf16*  rres = (bf16*)alloc((size_t)N * 128 * 2);
    bf16*  hA   = (bf16*)alloc((size_t)N * 128 * 2);
    bf16*  hB   = (bf16*)alloc((size_t)N * 128 * 2);
    (void)ws_size; (void)n_in; (void)out_size;

    hipMemsetAsync(cnt, 0, (size_t)N * 4, stream);
    const int eb = (E + 255) / 256;
    const int nb = (N + 1023) / 1024;    // 49 <= 64
    k_count<<<eb, 256, 0, stream>>>(ei, cnt, E);
    k_scan1<<<nb, 256, 0, stream>>>(cnt, ofs, bsum, N);
    k_scan2<<<1, 64, 0, stream>>>(bsum, bpre, nb);
    k_scan3<<<(N + 255) / 256, 256, 0, stream>>>(ofs, cur, bpre, N);
    k_fill<<<eb, 256, 0, stream>>>(ei, cur, csr, E);
    k_transpose<<<6, 256, 0, stream>>>(W1, R1w, W2, R2w, W3, R3w, WT);
    k_params<<<1, 128, 0, stream>>>(b1, R1b, g1, be1, rm1, rv1,
                                    b2, R2b, g2, be2, rm2, rv2, b3, R3b, prm);

    const int gx = (N + 127) / 128;
    const int nw = (N + 3) / 4;
    // layer 1 (A = f32 x)
    gemm_dual<float><<<dim3(gx, 2), 256, 0, stream>>>(x, WT, WT + 16384, xW, rres, N);
    k_prep8<<<nw, 256, 0, stream>>>(xW, as1, ad1, es, ed, N);
    k_agg8<<<nw, 256, 0, stream>>>(xW, es, ed, ofs, cur, csr, rres, prm, hA, N);
    // layer 2
    gemm_dual<bf16><<<dim3(gx, 2), 256, 0, stream>>>(hA, WT + 2 * 16384, WT + 3 * 16384, xW, rres, N);
    k_prep8<<<nw, 256, 0, stream>>>(xW, as2, ad2, es, ed, N);
    k_agg8<<<nw, 256, 0, stream>>>(xW, es, ed, ofs, cur, csr, rres, prm + 384, hB, N);
    // layer 3
    gemm_dual<bf16><<<dim3(gx, 2), 256, 0, stream>>>(hB, WT + 4 * 16384, WT + 5 * 16384, xW, rres, N);
    k_prep1<<<nw, 256, 0, stream>>>(xW, as3, ad3, es, ed, N);
    k_agg1<<<nw, 256, 0, stream>>>(xW, es, ed, ofs, cur, csr, rres, prm + 768, (float*)d_out, N);
}

// Round 4
// 350.243 us; speedup vs baseline: 1.5477x; 1.0591x over previous
//
#include <hip/hip_runtime.h>
#include <hip/hip_bf16.h>
#include <type_traits>

typedef __hip_bfloat16 bf16;
typedef __hip_bfloat162 bf162;
typedef short v8s __attribute__((ext_vector_type(8)));
typedef float v4f __attribute__((ext_vector_type(4)));

__device__ __forceinline__ float lrelu(float x) { return x > 0.f ? x : 0.2f * x; }
__device__ __forceinline__ float b2f(bf16 v) { return __bfloat162float(v); }

// ---------------- CSR build ----------------
__global__ void k_count(const int* __restrict__ ei, int* __restrict__ cnt, int E) {
    int i = blockIdx.x * 256 + threadIdx.x;
    if (i < E) atomicAdd(&cnt[ei[E + i]], 1);
}

__global__ void k_scan1(const int* __restrict__ cnt, int* __restrict__ ofs,
                        int* __restrict__ bsum, int n) {
    __shared__ int sh[256];
    int t = threadIdx.x;
    int base = blockIdx.x * 1024 + t * 4;
    int v[4]; int s = 0;
#pragma unroll
    for (int i = 0; i < 4; ++i) { v[i] = (base + i < n) ? cnt[base + i] : 0; s += v[i]; }
    sh[t] = s; __syncthreads();
    for (int o = 1; o < 256; o <<= 1) {
        int x = 0; if (t >= o) x = sh[t - o];
        __syncthreads();
        sh[t] += x;
        __syncthreads();
    }
    int excl = sh[t] - s;
#pragma unroll
    for (int i = 0; i < 4; ++i) { if (base + i < n) ofs[base + i] = excl; excl += v[i]; }
    if (t == 255) bsum[blockIdx.x] = sh[255];
}

__global__ void k_scan2(const int* __restrict__ bsum, int* __restrict__ bpre, int nb) {
    int l = threadIdx.x;                       // 64 threads, nb <= 64
    int v = (l < nb) ? bsum[l] : 0;
    int orig = v;
    for (int o = 1; o < 64; o <<= 1) {
        int x = __shfl_up(v, o);
        if (l >= o) v += x;
    }
    if (l < nb) bpre[l] = v - orig;
}

__global__ void k_scan3(int* __restrict__ ofs, int* __restrict__ cur,
                        const int* __restrict__ bpre, int n) {
    int i = blockIdx.x * 256 + threadIdx.x;
    if (i < n) { int v = ofs[i] + bpre[i >> 10]; ofs[i] = v; cur[i] = v; }
}

__global__ void k_fill(const int* __restrict__ ei, int* __restrict__ cur,
                       int* __restrict__ csr, int E) {
    int i = blockIdx.x * 256 + threadIdx.x;
    if (i < E) {
        int d = ei[E + i];
        int pos = atomicAdd(&cur[d], 1);
        csr[pos] = ei[i];
    }
}

// ---------------- weight transpose (f32 -> bf16) ----------------
__global__ void k_transpose(const float* __restrict__ s0, const float* __restrict__ s1,
                            const float* __restrict__ s2, const float* __restrict__ s3,
                            const float* __restrict__ s4, const float* __restrict__ s5,
                            bf16* __restrict__ wt) {
    const float* src;
    switch (blockIdx.x) {
        case 0: src = s0; break; case 1: src = s1; break; case 2: src = s2; break;
        case 3: src = s3; break; case 4: src = s4; break; default: src = s5; break;
    }
    bf16* dst = wt + blockIdx.x * 16384;
    for (int i = threadIdx.x; i < 16384; i += 256) {
        int k = i >> 7, n = i & 127;
        dst[n * 128 + k] = __float2bfloat16(src[i]);   // WT[n][k] = W[k][n]
    }
}

__global__ void k_params(const float* b1, const float* R1b, const float* g1, const float* be1,
                         const float* rm1, const float* rv1,
                         const float* b2, const float* R2b, const float* g2, const float* be2,
                         const float* rm2, const float* rv2,
                         const float* b3, const float* R3b, float* __restrict__ prm) {
    int c = threadIdx.x;
    if (c < 128) {
        float s1 = g1[c] * rsqrtf(rv1[c] + 1e-5f);
        prm[c]       = b1[c] + R1b[c];
        prm[128 + c] = s1;
        prm[256 + c] = be1[c] - rm1[c] * s1;
        float s2 = g2[c] * rsqrtf(rv2[c] + 1e-5f);
        prm[384 + c] = b2[c] + R2b[c];
        prm[512 + c] = s2;
        prm[640 + c] = be2[c] - rm2[c] * s2;
        prm[768 + c] = b3[c] + R3b[c];
    }
}

// ---------------- dual GEMM: O0 = A@W, O1 = A@R (both [n,128]@[128,128]) ----------------
template <typename T>
__global__ void gemm_dual(const T* __restrict__ A,
                          const bf16* __restrict__ BT0, const bf16* __restrict__ BT1,
                          bf16* __restrict__ O0, bf16* __restrict__ O1, int nrows) {
    __shared__ bf16 Ash[128 * 128];   // 32 KB, XOR-swizzled 16B chunks
    __shared__ bf16 Bsh[128 * 128];   // 32 KB
    const bf16* BT = (blockIdx.y == 0) ? BT0 : BT1;
    bf16* O = (blockIdx.y == 0) ? O0 : O1;
    const int t = threadIdx.x;
    const int rowbase = blockIdx.x * 128;
    {
        const int r = t >> 1, hf = t & 1;
        int gr = rowbase + r; if (gr >= nrows) gr = nrows - 1;
        const float4* bsrc = (const float4*)(BT + r * 128 + hf * 64);
        if constexpr (std::is_same<T, float>::value) {
            const float4* asrc = (const float4*)(A + (size_t)gr * 128 + hf * 64);
#pragma unroll
            for (int j = 0; j < 8; ++j) {
                float4 u = asrc[2 * j], w = asrc[2 * j + 1];
                union { bf16 h[8]; float4 f; } tmp;
                tmp.h[0] = __float2bfloat16(u.x); tmp.h[1] = __float2bfloat16(u.y);
                tmp.h[2] = __float2bfloat16(u.z); tmp.h[3] = __float2bfloat16(u.w);
                tmp.h[4] = __float2bfloat16(w.x); tmp.h[5] = __float2bfloat16(w.y);
                tmp.h[6] = __float2bfloat16(w.z); tmp.h[7] = __float2bfloat16(w.w);
                int c = hf * 8 + j, cp = c ^ (r & 7);
                *(float4*)(&Ash[r * 128 + cp * 8]) = tmp.f;
                *(float4*)(&Bsh[r * 128 + cp * 8]) = bsrc[j];
            }
        } else {
            const float4* asrc = (const float4*)(A + (size_t)gr * 128 + hf * 64);
#pragma unroll
            for (int j = 0; j < 8; ++j) {
                int c = hf * 8 + j, cp = c ^ (r & 7);
                *(float4*)(&Ash[r * 128 + cp * 8]) = asrc[j];
                *(float4*)(&Bsh[r * 128 + cp * 8]) = bsrc[j];
            }
        }
    }
    __syncthreads();
    const int wave = t >> 6, lane = t & 63, quad = lane >> 4, l16 = lane & 15;
    v4f acc[2][8];
#pragma unroll
    for (int i = 0; i < 2; ++i)
#pragma unroll
        for (int j = 0; j < 8; ++j) acc[i][j] = (v4f){0.f, 0.f, 0.f, 0.f};
#pragma unroll
    for (int kit = 0; kit < 4; ++kit) {
        v8s afr[2], bfr[8];
#pragma unroll
        for (int rt = 0; rt < 2; ++rt) {
            int row = wave * 32 + rt * 16 + l16;
            int cp = (kit * 4 + quad) ^ (row & 7);
            afr[rt] = *(const v8s*)(&Ash[row * 128 + cp * 8]);
        }
#pragma unroll
        for (int ct = 0; ct < 8; ++ct) {
            int nn = ct * 16 + l16;
            int cp = (kit * 4 + quad) ^ (nn & 7);
            bfr[ct] = *(const v8s*)(&Bsh[nn * 128 + cp * 8]);
        }
#pragma unroll
        for (int rt = 0; rt < 2; ++rt)
#pragma unroll
            for (int ct = 0; ct < 8; ++ct)
                acc[rt][ct] = __builtin_amdgcn_mfma_f32_16x16x32_bf16(afr[rt], bfr[ct], acc[rt][ct], 0, 0, 0);
    }
#pragma unroll
    for (int rt = 0; rt < 2; ++rt)
#pragma unroll
        for (int ct = 0; ct < 8; ++ct)
#pragma unroll
            for (int r = 0; r < 4; ++r) {
                int gr = rowbase + wave * 32 + rt * 16 + quad * 4 + r;
                if (gr < nrows) O[(size_t)gr * 128 + ct * 16 + l16] = __float2bfloat16(acc[rt][ct][r]);
            }
}

// ---------------- attention-logit prep ----------------
__global__ void k_prep8(const bf16* __restrict__ xW, const float* __restrict__ asrc,
                        const float* __restrict__ adst,
                        float* __restrict__ es, float* __restrict__ ed, int n) {
    int wave = threadIdx.x >> 6, lane = threadIdx.x & 63;
    int node = blockIdx.x * 4 + wave;
    if (node >= n) return;
    bf162 xp = *(const bf162*)(xW + (size_t)node * 128 + 2 * lane);
    float2 sp = *(const float2*)(asrc + 2 * lane);
    float2 dp = *(const float2*)(adst + 2 * lane);
    float x0 = b2f(xp.x), x1 = b2f(xp.y);
    float ps = x0 * sp.x + x1 * sp.y;
    float pd = x0 * dp.x + x1 * dp.y;
    for (int o = 1; o < 8; o <<= 1) { ps += __shfl_xor(ps, o); pd += __shfl_xor(pd, o); }
    if ((lane & 7) == 0) {
        int h = lane >> 3;
        es[node * 8 + h] = ps;
        ed[node * 8 + h] = pd;
    }
}

__global__ void k_prep1(const bf16* __restrict__ xW, const float* __restrict__ asrc,
                        const float* __restrict__ adst,
                        float* __restrict__ es, float* __restrict__ ed, int n) {
    int wave = threadIdx.x >> 6, lane = threadIdx.x & 63;
    int node = blockIdx.x * 4 + wave;
    if (node >= n) return;
    bf162 xp = *(const bf162*)(xW + (size_t)node * 128 + 2 * lane);
    float2 sp = *(const float2*)(asrc + 2 * lane);
    float2 dp = *(const float2*)(adst + 2 * lane);
    float x0 = b2f(xp.x), x1 = b2f(xp.y);
    float ps = x0 * sp.x + x1 * sp.y;
    float pd = x0 * dp.x + x1 * dp.y;
    for (int o = 1; o < 64; o <<= 1) { ps += __shfl_xor(ps, o); pd += __shfl_xor(pd, o); }
    if (lane == 0) { es[node] = ps; ed[node] = pd; }
}

// ---------------- aggregation: 4 edges in flight per wave, 8 heads ----------------
// 16 lanes per edge-group; lane covers 8 contiguous channels (one dwordx4).
__global__ void k_agg8(const bf16* __restrict__ xW, const float* __restrict__ es,
                       const float* __restrict__ ed,
                       const int* __restrict__ ofs, const int* __restrict__ cur,
                       const int* __restrict__ csr,
                       const bf16* __restrict__ rres, const float* __restrict__ prm,
                       bf16* __restrict__ hout, int n) {
    int wave = threadIdx.x >> 6, lane = threadIdx.x & 63;
    int node = blockIdx.x * 4 + wave;
    if (node >= n) return;
    const int g = lane >> 4, l16 = lane & 15;
    const int c0 = l16 * 8;          // channel base: 8 channels/lane
    const int h = l16 >> 1;          // head of those channels
    float edv = ed[node * 8 + h];
    int beg = ofs[node], end = cur[node];
    float acc[8];
    float den = 0.f;
#pragma unroll
    for (int i = 0; i < 8; ++i) acc[i] = 0.f;
    if (g == 0) {                    // self loop handled by group 0
        float ws = __expf(lrelu(es[node * 8 + h] + edv));
        v8s xv = *(const v8s*)(xW + (size_t)node * 128 + c0);
        const bf16* xb = (const bf16*)&xv;
        den = ws;
#pragma unroll
        for (int i = 0; i < 8; ++i) acc[i] = ws * b2f(xb[i]);
    }
    for (int base = beg; base < end; base += 64) {
        int m = end - base; if (m > 64) m = 64;
        int idx = (lane < m) ? csr[base + lane] : node;   // pad with safe index
        for (int j = 0; j < m; j += 4) {
            int s = __shfl(idx, j + g);
            float e = es[s * 8 + h];
            v8s xv = *(const v8s*)(xW + (size_t)s * 128 + c0);
            float w = ((j + g) < m) ? __expf(lrelu(e + edv)) : 0.f;
            const bf16* xb = (const bf16*)&xv;
            den += w;
#pragma unroll
            for (int i = 0; i < 8; ++i) acc[i] += w * b2f(xb[i]);
        }
    }
    // reduce across the 4 edge-groups (lanes differing in bits 4,5)
    den += __shfl_xor(den, 16); den += __shfl_xor(den, 32);
#pragma unroll
    for (int i = 0; i < 8; ++i) {
        acc[i] += __shfl_xor(acc[i], 16);
        acc[i] += __shfl_xor(acc[i], 32);
    }
    if (g == 0) {
        float inv = 1.f / den;
        v8s rv = *(const v8s*)(rres + (size_t)node * 128 + c0);
        const bf16* rb = (const bf16*)&rv;
        bf16 outv[8];
#pragma unroll
        for (int i = 0; i < 8; ++i) {
            int c = c0 + i;
            float v = acc[i] * inv + prm[c] + b2f(rb[i]);
            v = fmaxf(v * prm[128 + c] + prm[256 + c], 0.f);
            outv[i] = __float2bfloat16(v);
        }
        *(v8s*)(hout + (size_t)node * 128 + c0) = *(v8s*)outv;
    }
}

// ---------------- aggregation: 4 edges in flight, 1 head, writes final out (f32) ----------------
__global__ void k_agg1(const bf16* __restrict__ xW, const float* __restrict__ es,
                       const float* __restrict__ ed,
                       const int* __restrict__ ofs, const int* __restrict__ cur,
                       const int* __restrict__ csr,
                       const bf16* __restrict__ rres, const float* __restrict__ bias,
                       float* __restrict__ out, int n) {
    int wave = threadIdx.x >> 6, lane = threadIdx.x & 63;
    int node = blockIdx.x * 4 + wave;
    if (node >= n) return;
    const int g = lane >> 4, l16 = lane & 15;
    const int c0 = l16 * 8;
    float edv = ed[node];
    int beg = ofs[node], end = cur[node];
    float acc[8];
    float den = 0.f;
#pragma unroll
    for (int i = 0; i < 8; ++i) acc[i] = 0.f;
    if (g == 0) {
        float ws = __expf(lrelu(es[node] + edv));
        v8s xv = *(const v8s*)(xW + (size_t)node * 128 + c0);
        const bf16* xb = (const bf16*)&xv;
        den = ws;
#pragma unroll
        for (int i = 0; i < 8; ++i) acc[i] = ws * b2f(xb[i]);
    }
    for (int base = beg; base < end; base += 64) {
        int m = end - base; if (m > 64) m = 64;
        int idx = (lane < m) ? csr[base + lane] : node;
        for (int j = 0; j < m; j += 4) {
            int s = __shfl(idx, j + g);
            float e = es[s];
            v8s xv = *(const v8s*)(xW + (size_t)s * 128 + c0);
            float w = ((j + g) < m) ? __expf(lrelu(e + edv)) : 0.f;
            const bf16* xb = (const bf16*)&xv;
            den += w;
#pragma unroll
            for (int i = 0; i < 8; ++i) acc[i] += w * b2f(xb[i]);
        }
    }
    den += __shfl_xor(den, 16); den += __shfl_xor(den, 32);
#pragma unroll
    for (int i = 0; i < 8; ++i) {
        acc[i] += __shfl_xor(acc[i], 16);
        acc[i] += __shfl_xor(acc[i], 32);
    }
    if (g == 0) {
        float inv = 1.f / den;
        v8s rv = *(const v8s*)(rres + (size_t)node * 128 + c0);
        const bf16* rb = (const bf16*)&rv;
        float4 o0, o1;
        float ov[8];
#pragma unroll
        for (int i = 0; i < 8; ++i)
            ov[i] = acc[i] * inv + bias[c0 + i] + b2f(rb[i]);
        o0.x = ov[0]; o0.y = ov[1]; o0.z = ov[2]; o0.w = ov[3];
        o1.x = ov[4]; o1.y = ov[5]; o1.z = ov[6]; o1.w = ov[7];
        *(float4*)(out + (size_t)node * 128 + c0) = o0;
        *(float4*)(out + (size_t)node * 128 + c0 + 4) = o1;
    }
}

extern "C" void kernel_launch(void* const* d_in, const int* in_sizes, int n_in,
                              void* d_out, int out_size, void* d_ws, size_t ws_size,
                              hipStream_t stream) {
    const float* x   = (const float*)d_in[0];
    const int*   ei  = (const int*)d_in[1];
    const float* W1  = (const float*)d_in[2];
    const float* as1 = (const float*)d_in[3];
    const float* ad1 = (const float*)d_in[4];
    const float* b1  = (const float*)d_in[5];
    const float* W2  = (const float*)d_in[6];
    const float* as2 = (const float*)d_in[7];
    const float* ad2 = (const float*)d_in[8];
    const float* b2  = (const float*)d_in[9];
    const float* W3  = (const float*)d_in[10];
    const float* as3 = (const float*)d_in[11];
    const float* ad3 = (const float*)d_in[12];
    const float* b3  = (const float*)d_in[13];
    const float* R1w = (const float*)d_in[14];
    const float* R1b = (const float*)d_in[15];
    const float* R2w = (const float*)d_in[16];
    const float* R2b = (const float*)d_in[17];
    const float* R3w = (const float*)d_in[18];
    const float* R3b = (const float*)d_in[19];
    const float* g1  = (const float*)d_in[20];
    const float* be1 = (const float*)d_in[21];
    const float* rm1 = (const float*)d_in[22];
    const float* rv1 = (const float*)d_in[23];
    const float* g2  = (const float*)d_in[24];
    const float* be2 = (const float*)d_in[25];
    const float* rm2 = (const float*)d_in[26];
    const float* rv2 = (const float*)d_in[27];

    const int N = in_sizes[0] / 128;
    const int E = in_sizes[1] / 2;

    char* p = (char*)d_ws;
    size_t off = 0;
    auto alloc = [&](size_t b) { void* r = p + off; off = (off + b + 255) & ~(size_t)255; return r; };
    int*   cnt  = (int*)alloc((size_t)N * 4);
    int*   ofs  = (int*)alloc((size_t)N * 4);
    int*   cur  = (int*)alloc((size_t)N * 4);
    int*   bsum = (int*)alloc(64 * 4);
    int*   bpre = (int*)alloc(64 * 4);
    int*   csr  = (int*)alloc((size_t)E * 4);
    bf16*  WT   = (bf16*)alloc((size_t)6 * 16384 * 2);
    float* prm  = (float*)alloc(896 * 4);
    float* es   = (float*)alloc((size_t)N * 8 * 4);
    float* ed   = (float*)alloc((size_t)N * 8 * 4);
    bf16*  xW   = (bf16*)alloc((size_t)N * 128 * 2);
    bf16*  rres = (bf16*)alloc((size_t)N * 128 * 2);
    bf16*  hA   = (bf16*)alloc((size_t)N * 128 * 2);
    bf16*  hB   = (bf16*)alloc((size_t)N * 128 * 2);
    (void)ws_size; (void)n_in; (void)out_size;

    hipMemsetAsync(cnt, 0, (size_t)N * 4, stream);
    const int eb = (E + 255) / 256;
    const int nb = (N + 1023) / 1024;    // 49 <= 64
    k_count<<<eb, 256, 0, stream>>>(ei, cnt, E);
    k_scan1<<<nb, 256, 0, stream>>>(cnt, ofs, bsum, N);
    k_scan2<<<1, 64, 0, stream>>>(bsum, bpre, nb);
    k_scan3<<<(N + 255) / 256, 256, 0, stream>>>(ofs, cur, bpre, N);
    k_fill<<<eb, 256, 0, stream>>>(ei, cur, csr, E);
    k_transpose<<<6, 256, 0, stream>>>(W1, R1w, W2, R2w, W3, R3w, WT);
    k_params<<<1, 128, 0, stream>>>(b1, R1b, g1, be1, rm1, rv1,
                                    b2, R2b, g2, be2, rm2, rv2, b3, R3b, prm);

    const int gx = (N + 127) / 128;
    const int nw = (N + 3) / 4;
    // layer 1 (A = f32 x)
    gemm_dual<float><<<dim3(gx, 2), 256, 0, stream>>>(x, WT, WT + 16384, xW, rres, N);
    k_prep8<<<nw, 256, 0, stream>>>(xW, as1, ad1, es, ed, N);
    k_agg8<<<nw, 256, 0, stream>>>(xW, es, ed, ofs, cur, csr, rres, prm, hA, N);
    // layer 2
    gemm_dual<bf16><<<dim3(gx, 2), 256, 0, stream>>>(hA, WT + 2 * 16384, WT + 3 * 16384, xW, rres, N);
    k_prep8<<<nw, 256, 0, stream>>>(xW, as2, ad2, es, ed, N);
    k_agg8<<<nw, 256, 0, stream>>>(xW, es, ed, ofs, cur, csr, rres, prm + 384, hB, N);
    // layer 3
    gemm_dual<bf16><<<dim3(gx, 2), 256, 0, stream>>>(hB, WT + 4 * 16384, WT + 5 * 16384, xW, rres, N);
    k_prep1<<<nw, 256, 0, stream>>>(xW, as3, ad3, es, ed, N);
    k_agg1<<<nw, 256, 0, stream>>>(xW, es, ed, ofs, cur, csr, rres, prm + 768, (float*)d_out, N);
}

// Round 5
// 346.691 us; speedup vs baseline: 1.5635x; 1.0102x over previous
//
#include <hip/hip_runtime.h>
#include <hip/hip_bf16.h>
#include <type_traits>

typedef __hip_bfloat16 bf16;
typedef __hip_bfloat162 bf162;
typedef short v8s __attribute__((ext_vector_type(8)));
typedef float v4f __attribute__((ext_vector_type(4)));

__device__ __forceinline__ float lrelu(float x) { return x > 0.f ? x : 0.2f * x; }
__device__ __forceinline__ float b2f(bf16 v) { return __bfloat162float(v); }

// ---------------- CSR build ----------------
__global__ void k_count(const int* __restrict__ ei, int* __restrict__ cnt, int E) {
    int i = blockIdx.x * 256 + threadIdx.x;
    if (i < E) atomicAdd(&cnt[ei[E + i]], 1);
}

__global__ void k_scan1(const int* __restrict__ cnt, int* __restrict__ ofs,
                        int* __restrict__ bsum, int n) {
    __shared__ int sh[256];
    int t = threadIdx.x;
    int base = blockIdx.x * 1024 + t * 4;
    int v[4]; int s = 0;
#pragma unroll
    for (int i = 0; i < 4; ++i) { v[i] = (base + i < n) ? cnt[base + i] : 0; s += v[i]; }
    sh[t] = s; __syncthreads();
    for (int o = 1; o < 256; o <<= 1) {
        int x = 0; if (t >= o) x = sh[t - o];
        __syncthreads();
        sh[t] += x;
        __syncthreads();
    }
    int excl = sh[t] - s;
#pragma unroll
    for (int i = 0; i < 4; ++i) { if (base + i < n) ofs[base + i] = excl; excl += v[i]; }
    if (t == 255) bsum[blockIdx.x] = sh[255];
}

__global__ void k_scan2(const int* __restrict__ bsum, int* __restrict__ bpre, int nb) {
    int l = threadIdx.x;                       // 64 threads, nb <= 64
    int v = (l < nb) ? bsum[l] : 0;
    int orig = v;
    for (int o = 1; o < 64; o <<= 1) {
        int x = __shfl_up(v, o);
        if (l >= o) v += x;
    }
    if (l < nb) bpre[l] = v - orig;
}

__global__ void k_scan3(int* __restrict__ ofs, int* __restrict__ cur,
                        const int* __restrict__ bpre, int n) {
    int i = blockIdx.x * 256 + threadIdx.x;
    if (i < n) { int v = ofs[i] + bpre[i >> 10]; ofs[i] = v; cur[i] = v; }
}

__global__ void k_fill(const int* __restrict__ ei, int* __restrict__ cur,
                       int* __restrict__ csr, int E) {
    int i = blockIdx.x * 256 + threadIdx.x;
    if (i < E) {
        int d = ei[E + i];
        int pos = atomicAdd(&cur[d], 1);
        csr[pos] = ei[i];
    }
}

// ---------------- weight transpose + attn-fold + BN params (one kernel) ----------------
// WT layout per matrix: 144 rows x 128 (rows 0..127 = W^T, 128..135 = V_src, 136..143 = V_dst)
__global__ void k_trans(const float* __restrict__ s0, const float* __restrict__ s1,
                        const float* __restrict__ s2, const float* __restrict__ s3,
                        const float* __restrict__ s4, const float* __restrict__ s5,
                        const float* __restrict__ as1, const float* __restrict__ ad1,
                        const float* __restrict__ as2, const float* __restrict__ ad2,
                        const float* __restrict__ as3, const float* __restrict__ ad3,
                        const float* b1, const float* R1b, const float* g1, const float* be1,
                        const float* rm1, const float* rv1,
                        const float* b2, const float* R2b, const float* g2, const float* be2,
                        const float* rm2, const float* rv2,
                        const float* b3, const float* R3b,
                        bf16* __restrict__ wt, float* __restrict__ prm) {
    int b = blockIdx.x;
    int t = threadIdx.x;
    if (b == 6) {                      // BN/bias params
        int c = t;
        if (c < 128) {
            float s1v = g1[c] * rsqrtf(rv1[c] + 1e-5f);
            prm[c]       = b1[c] + R1b[c];
            prm[128 + c] = s1v;
            prm[256 + c] = be1[c] - rm1[c] * s1v;
            float s2v = g2[c] * rsqrtf(rv2[c] + 1e-5f);
            prm[384 + c] = b2[c] + R2b[c];
            prm[512 + c] = s2v;
            prm[640 + c] = be2[c] - rm2[c] * s2v;
            prm[768 + c] = b3[c] + R3b[c];
        }
        return;
    }
    const float* src;
    switch (b) {
        case 0: src = s0; break; case 1: src = s1; break; case 2: src = s2; break;
        case 3: src = s3; break; case 4: src = s4; break; default: src = s5; break;
    }
    bf16* dst = wt + (size_t)b * 18432;
    for (int i = t; i < 16384; i += 256) {
        int k = i >> 7, n = i & 127;
        dst[n * 128 + k] = __float2bfloat16(src[i]);   // WT[n][k] = W[k][n]
    }
    if ((b & 1) == 0) {                // W matrices: fold a_src/a_dst into extra rows
        int layer = b >> 1;
        if (layer < 2) {
            const float* asr = (layer == 0) ? as1 : as2;
            const float* ads = (layer == 0) ? ad1 : ad2;
            for (int i = t; i < 2048; i += 256) {
                int row = i >> 7, k = i & 127, h = row & 7;
                const float* av = (row < 8) ? asr : ads;
                float s = 0.f;
#pragma unroll
                for (int c = 0; c < 16; ++c) s += src[k * 128 + h * 16 + c] * av[h * 16 + c];
                dst[(128 + row) * 128 + k] = __float2bfloat16(s);
            }
        } else {                       // layer 3: single head over 128 channels
            for (int i = t; i < 2048; i += 256) {
                int row = i >> 7, k = i & 127;
                float s = 0.f;
                if (row == 0 || row == 8) {
                    const float* av = (row == 0) ? as3 : ad3;
                    for (int c = 0; c < 128; ++c) s += src[k * 128 + c] * av[c];
                }
                dst[(128 + row) * 128 + k] = __float2bfloat16(s);
            }
        }
    } else {                           // R matrices: zero the extra rows
        for (int i = t; i < 2048; i += 256)
            dst[16384 + i] = __float2bfloat16(0.f);
    }
}

// ---------------- dual GEMM + fused attention logits ----------------
// O0 = A@W (+ es/ed from folded V columns), O1 = A@R. B is 144x128 (BT layout).
// mode: 1 = 8-head es/ed, 2 = 1-head es/ed (only y==0 writes es/ed).
template <typename T>
__global__ void gemm_dual(const T* __restrict__ A,
                          const bf16* __restrict__ BT0, const bf16* __restrict__ BT1,
                          bf16* __restrict__ O0, bf16* __restrict__ O1,
                          float* __restrict__ es, float* __restrict__ ed,
                          int mode, int nrows) {
    __shared__ bf16 Ash[128 * 128];   // 32 KB
    __shared__ bf16 Bsh[144 * 128];   // 36 KB
    const bf16* BT = (blockIdx.y == 0) ? BT0 : BT1;
    bf16* O = (blockIdx.y == 0) ? O0 : O1;
    const int t = threadIdx.x;
    const int rowbase = blockIdx.x * 128;
    {   // A staging (f32 converts to bf16)
        const int r = t >> 1, hf = t & 1;
        int gr = rowbase + r; if (gr >= nrows) gr = nrows - 1;
        if constexpr (std::is_same<T, float>::value) {
            const float4* asrc = (const float4*)(A + (size_t)gr * 128 + hf * 64);
#pragma unroll
            for (int j = 0; j < 8; ++j) {
                float4 u = asrc[2 * j], w = asrc[2 * j + 1];
                union { bf16 h[8]; float4 f; } tmp;
                tmp.h[0] = __float2bfloat16(u.x); tmp.h[1] = __float2bfloat16(u.y);
                tmp.h[2] = __float2bfloat16(u.z); tmp.h[3] = __float2bfloat16(u.w);
                tmp.h[4] = __float2bfloat16(w.x); tmp.h[5] = __float2bfloat16(w.y);
                tmp.h[6] = __float2bfloat16(w.z); tmp.h[7] = __float2bfloat16(w.w);
                int c = hf * 8 + j, cp = c ^ (r & 7);
                *(float4*)(&Ash[r * 128 + cp * 8]) = tmp.f;
            }
        } else {
            const float4* asrc = (const float4*)(A + (size_t)gr * 128 + hf * 64);
#pragma unroll
            for (int j = 0; j < 8; ++j) {
                int c = hf * 8 + j, cp = c ^ (r & 7);
                *(float4*)(&Ash[r * 128 + cp * 8]) = asrc[j];
            }
        }
    }
    // B staging: 144 rows, 288 (row,half) slots over 256 threads
    for (int s = t; s < 288; s += 256) {
        int r = s >> 1, hf = s & 1;
        const float4* bsrc = (const float4*)(BT + r * 128 + hf * 64);
#pragma unroll
        for (int j = 0; j < 8; ++j) {
            int c = hf * 8 + j, cp = c ^ (r & 7);
            *(float4*)(&Bsh[r * 128 + cp * 8]) = bsrc[j];
        }
    }
    __syncthreads();
    const int wave = t >> 6, lane = t & 63, quad = lane >> 4, l16 = lane & 15;
    v4f acc[2][9];
#pragma unroll
    for (int i = 0; i < 2; ++i)
#pragma unroll
        for (int j = 0; j < 9; ++j) acc[i][j] = (v4f){0.f, 0.f, 0.f, 0.f};
#pragma unroll
    for (int kit = 0; kit < 4; ++kit) {
        v8s afr[2], bfr[9];
#pragma unroll
        for (int rt = 0; rt < 2; ++rt) {
            int row = wave * 32 + rt * 16 + l16;
            int cp = (kit * 4 + quad) ^ (row & 7);
            afr[rt] = *(const v8s*)(&Ash[row * 128 + cp * 8]);
        }
#pragma unroll
        for (int ct = 0; ct < 9; ++ct) {
            int nn = ct * 16 + l16;
            int cp = (kit * 4 + quad) ^ (nn & 7);
            bfr[ct] = *(const v8s*)(&Bsh[nn * 128 + cp * 8]);
        }
#pragma unroll
        for (int rt = 0; rt < 2; ++rt)
#pragma unroll
            for (int ct = 0; ct < 9; ++ct)
                acc[rt][ct] = __builtin_amdgcn_mfma_f32_16x16x32_bf16(afr[rt], bfr[ct], acc[rt][ct], 0, 0, 0);
    }
#pragma unroll
    for (int rt = 0; rt < 2; ++rt)
#pragma unroll
        for (int ct = 0; ct < 8; ++ct)
#pragma unroll
            for (int r = 0; r < 4; ++r) {
                int gr = rowbase + wave * 32 + rt * 16 + quad * 4 + r;
                if (gr < nrows) O[(size_t)gr * 128 + ct * 16 + l16] = __float2bfloat16(acc[rt][ct][r]);
            }
    if (mode != 0 && blockIdx.y == 0) {   // es/ed from the 9th tile (cols 128..143)
#pragma unroll
        for (int rt = 0; rt < 2; ++rt)
#pragma unroll
            for (int r = 0; r < 4; ++r) {
                int gr = rowbase + wave * 32 + rt * 16 + quad * 4 + r;
                if (gr < nrows) {
                    float v = acc[rt][8][r];
                    if (mode == 1) {
                        if (l16 < 8) es[(size_t)gr * 8 + l16] = v;
                        else         ed[(size_t)gr * 8 + (l16 - 8)] = v;
                    } else {
                        if (l16 == 0) es[gr] = v;
                        else if (l16 == 8) ed[gr] = v;
                    }
                }
            }
    }
}

// ---------------- aggregation: batched edge-weight phase + 4-way gather, 8 heads ----------------
__global__ void k_agg8(const bf16* __restrict__ xW, const float* __restrict__ es8,
                       const float* __restrict__ ed8,
                       const int* __restrict__ ofs, const int* __restrict__ cur,
                       const int* __restrict__ csr,
                       const bf16* __restrict__ rres, const float* __restrict__ prm,
                       bf16* __restrict__ hout, int n) {
    int wave = threadIdx.x >> 6, lane = threadIdx.x & 63;
    int node = blockIdx.x * 4 + wave;
    if (node >= n) return;
    const int g = lane >> 4, l16 = lane & 15;
    const int c0 = l16 * 8;          // 8 channels per lane
    const int hc = l16 >> 1;         // head of this lane's channels
    const int he = lane & 7;         // head this lane serves in the weight phase
    float edw = ed8[(size_t)node * 8 + he];
    float wselfh = __expf(lrelu(es8[(size_t)node * 8 + he] + edw));  // self weight for head he
    float acc[8]; float den = 0.f;
#pragma unroll
    for (int i = 0; i < 8; ++i) acc[i] = 0.f;
    {
        float ws = __shfl(wselfh, hc);       // lane hc holds head hc's self weight
        if (g == 0) {
            v8s xv = *(const v8s*)(xW + (size_t)node * 128 + c0);
            const bf16* xb = (const bf16*)&xv;
            den = ws;
#pragma unroll
            for (int i = 0; i < 8; ++i) acc[i] = ws * b2f(xb[i]);
        }
    }
    int beg = ofs[node], end = cur[node];
    for (int base = beg; base < end; base += 64) {
        int m = end - base; if (m > 64) m = 64;
        int idx = (lane < m) ? csr[base + lane] : node;   // padded safe
        for (int sub = 0; sub * 8 < m; ++sub) {
            // weight phase: lane serves (edge sub*8 + lane>>3, head lane&7)
            int e = sub * 8 + (lane >> 3);
            int sidx = __shfl(idx, e & 63);
            float esv = es8[(size_t)sidx * 8 + he];
            float w = (e < m) ? __expf(lrelu(esv + edw)) : 0.f;
            // accumulate the 8 edges: group g takes edges sub*8 + {g, 4+g}
#pragma unroll
            for (int jj = 0; jj < 2; ++jj) {
                int jo = jj * 4 + g;
                int j = sub * 8 + jo;
                int sv = __shfl(idx, j & 63);
                float wj = __shfl(w, jo * 8 + hc);
                v8s xv = *(const v8s*)(xW + (size_t)sv * 128 + c0);
                const bf16* xb = (const bf16*)&xv;
                den += wj;
#pragma unroll
                for (int i = 0; i < 8; ++i) acc[i] += wj * b2f(xb[i]);
            }
        }
    }
    den += __shfl_xor(den, 16); den += __shfl_xor(den, 32);
#pragma unroll
    for (int i = 0; i < 8; ++i) {
        acc[i] += __shfl_xor(acc[i], 16);
        acc[i] += __shfl_xor(acc[i], 32);
    }
    if (g == 0) {
        float inv = 1.f / den;
        v8s rv = *(const v8s*)(rres + (size_t)node * 128 + c0);
        const bf16* rb = (const bf16*)&rv;
        bf16 outv[8];
#pragma unroll
        for (int i = 0; i < 8; ++i) {
            int c = c0 + i;
            float v = acc[i] * inv + prm[c] + b2f(rb[i]);
            v = fmaxf(v * prm[128 + c] + prm[256 + c], 0.f);
            outv[i] = __float2bfloat16(v);
        }
        *(v8s*)(hout + (size_t)node * 128 + c0) = *(v8s*)outv;
    }
}

// ---------------- aggregation: 1 head, batched weights, writes final out (f32) ----------------
__global__ void k_agg1(const bf16* __restrict__ xW, const float* __restrict__ es,
                       const float* __restrict__ ed,
                       const int* __restrict__ ofs, const int* __restrict__ cur,
                       const int* __restrict__ csr,
                       const bf16* __restrict__ rres, const float* __restrict__ bias,
                       float* __restrict__ out, int n) {
    int wave = threadIdx.x >> 6, lane = threadIdx.x & 63;
    int node = blockIdx.x * 4 + wave;
    if (node >= n) return;
    const int g = lane >> 4, l16 = lane & 15;
    const int c0 = l16 * 8;
    float edv = ed[node];
    float wself = __expf(lrelu(es[node] + edv));
    float acc[8]; float den = 0.f;
#pragma unroll
    for (int i = 0; i < 8; ++i) acc[i] = 0.f;
    if (g == 0) {
        v8s xv = *(const v8s*)(xW + (size_t)node * 128 + c0);
        const bf16* xb = (const bf16*)&xv;
        den = wself;
#pragma unroll
        for (int i = 0; i < 8; ++i) acc[i] = wself * b2f(xb[i]);
    }
    int beg = ofs[node], end = cur[node];
    for (int base = beg; base < end; base += 64) {
        int m = end - base; if (m > 64) m = 64;
        int idx = (lane < m) ? csr[base + lane] : node;
        float w = (lane < m) ? __expf(lrelu(es[idx] + edv)) : 0.f;  // 64 edge weights in flight
        for (int j = 0; j < m; j += 4) {
            int jl = j + g;
            int sv = __shfl(idx, jl & 63);
            float wj = __shfl(w, jl & 63);
            if (jl >= m) wj = 0.f;
            v8s xv = *(const v8s*)(xW + (size_t)sv * 128 + c0);
            const bf16* xb = (const bf16*)&xv;
            den += wj;
#pragma unroll
            for (int i = 0; i < 8; ++i) acc[i] += wj * b2f(xb[i]);
        }
    }
    den += __shfl_xor(den, 16); den += __shfl_xor(den, 32);
#pragma unroll
    for (int i = 0; i < 8; ++i) {
        acc[i] += __shfl_xor(acc[i], 16);
        acc[i] += __shfl_xor(acc[i], 32);
    }
    if (g == 0) {
        float inv = 1.f / den;
        v8s rv = *(const v8s*)(rres + (size_t)node * 128 + c0);
        const bf16* rb = (const bf16*)&rv;
        float ov[8];
#pragma unroll
        for (int i = 0; i < 8; ++i)
            ov[i] = acc[i] * inv + bias[c0 + i] + b2f(rb[i]);
        float4 o0, o1;
        o0.x = ov[0]; o0.y = ov[1]; o0.z = ov[2]; o0.w = ov[3];
        o1.x = ov[4]; o1.y = ov[5]; o1.z = ov[6]; o1.w = ov[7];
        *(float4*)(out + (size_t)node * 128 + c0) = o0;
        *(float4*)(out + (size_t)node * 128 + c0 + 4) = o1;
    }
}

extern "C" void kernel_launch(void* const* d_in, const int* in_sizes, int n_in,
                              void* d_out, int out_size, void* d_ws, size_t ws_size,
                              hipStream_t stream) {
    const float* x   = (const float*)d_in[0];
    const int*   ei  = (const int*)d_in[1];
    const float* W1  = (const float*)d_in[2];
    const float* as1 = (const float*)d_in[3];
    const float* ad1 = (const float*)d_in[4];
    const float* b1  = (const float*)d_in[5];
    const float* W2  = (const float*)d_in[6];
    const float* as2 = (const float*)d_in[7];
    const float* ad2 = (const float*)d_in[8];
    const float* b2  = (const float*)d_in[9];
    const float* W3  = (const float*)d_in[10];
    const float* as3 = (const float*)d_in[11];
    const float* ad3 = (const float*)d_in[12];
    const float* b3  = (const float*)d_in[13];
    const float* R1w = (const float*)d_in[14];
    const float* R1b = (const float*)d_in[15];
    const float* R2w = (const float*)d_in[16];
    const float* R2b = (const float*)d_in[17];
    const float* R3w = (const float*)d_in[18];
    const float* R3b = (const float*)d_in[19];
    const float* g1  = (const float*)d_in[20];
    const float* be1 = (const float*)d_in[21];
    const float* rm1 = (const float*)d_in[22];
    const float* rv1 = (const float*)d_in[23];
    const float* g2  = (const float*)d_in[24];
    const float* be2 = (const float*)d_in[25];
    const float* rm2 = (const float*)d_in[26];
    const float* rv2 = (const float*)d_in[27];

    const int N = in_sizes[0] / 128;
    const int E = in_sizes[1] / 2;

    char* p = (char*)d_ws;
    size_t off = 0;
    auto alloc = [&](size_t b) { void* r = p + off; off = (off + b + 255) & ~(size_t)255; return r; };
    int*   cnt  = (int*)alloc((size_t)N * 4);
    int*   ofs  = (int*)alloc((size_t)N * 4);
    int*   cur  = (int*)alloc((size_t)N * 4);
    int*   bsum = (int*)alloc(64 * 4);
    int*   bpre = (int*)alloc(64 * 4);
    int*   csr  = (int*)alloc((size_t)E * 4);
    bf16*  WT   = (bf16*)alloc((size_t)6 * 18432 * 2);
    float* prm  = (float*)alloc(896 * 4);
    float* es   = (float*)alloc((size_t)N * 8 * 4);
    float* ed   = (float*)alloc((size_t)N * 8 * 4);
    bf16*  xW   = (bf16*)alloc((size_t)N * 128 * 2);
    bf16*  rres = (bf16*)alloc((size_t)N * 128 * 2);
    bf16*  hA   = (bf16*)alloc((size_t)N * 128 * 2);
    bf16*  hB   = (bf16*)alloc((size_t)N * 128 * 2);
    (void)ws_size; (void)n_in; (void)out_size;

    hipMemsetAsync(cnt, 0, (size_t)N * 4, stream);
    const int eb = (E + 255) / 256;
    const int nb = (N + 1023) / 1024;    // 49 <= 64
    k_count<<<eb, 256, 0, stream>>>(ei, cnt, E);
    k_scan1<<<nb, 256, 0, stream>>>(cnt, ofs, bsum, N);
    k_scan2<<<1, 64, 0, stream>>>(bsum, bpre, nb);
    k_scan3<<<(N + 255) / 256, 256, 0, stream>>>(ofs, cur, bpre, N);
    k_fill<<<eb, 256, 0, stream>>>(ei, cur, csr, E);
    k_trans<<<7, 256, 0, stream>>>(W1, R1w, W2, R2w, W3, R3w,
                                   as1, ad1, as2, ad2, as3, ad3,
                                   b1, R1b, g1, be1, rm1, rv1,
                                   b2, R2b, g2, be2, rm2, rv2, b3, R3b,
                                   WT, prm);

    const int gx = (N + 127) / 128;
    const int nw = (N + 3) / 4;
    // layer 1 (A = f32 x)
    gemm_dual<float><<<dim3(gx, 2), 256, 0, stream>>>(x, WT, WT + 18432, xW, rres, es, ed, 1, N);
    k_agg8<<<nw, 256, 0, stream>>>(xW, es, ed, ofs, cur, csr, rres, prm, hA, N);
    // layer 2
    gemm_dual<bf16><<<dim3(gx, 2), 256, 0, stream>>>(hA, WT + 2 * 18432, WT + 3 * 18432, xW, rres, es, ed, 1, N);
    k_agg8<<<nw, 256, 0, stream>>>(xW, es, ed, ofs, cur, csr, rres, prm + 384, hB, N);
    // layer 3
    gemm_dual<bf16><<<dim3(gx, 2), 256, 0, stream>>>(hB, WT + 4 * 18432, WT + 5 * 18432, xW, rres, es, ed, 2, N);
    k_agg1<<<nw, 256, 0, stream>>>(xW, es, ed, ofs, cur, csr, rres, prm + 768, (float*)d_out, N);
}